// Round 1
// 219.450 us; speedup vs baseline: 1.0899x; 1.0899x over previous
//
#include <hip/hip_runtime.h>

// CompositeValueNoise R9: 1024-bucket (16x8x8) counting sort; main kernel
// stages the FULL bucket's grid slices for all 4 levels to LDS in one pass
// (3099 float4 = 49.6 KB), then streams sorted points coalesced, evaluates
// LDS-only, writes tmp coalesced. No fine sort, no point payload in LDS,
// one barrier per block (was 9+). 49.6 KB LDS -> 2 blocks/CU = 32 waves/CU.
// rank written coalesced in scatter; permute epilogue gathers tmp[rank[i]].

#define NB 1024                // 16 x 8 x 8 buckets
#define PTS_PER_BLK 4096
#define CHUNK 32
#define SC_THREADS 1024
#define SC_PPT (PTS_PER_BLK / SC_THREADS)
#define H_THREADS 256
#define H_PPT (PTS_PER_BLK / H_THREADS)
#define MT 1024                // main kernel threads

__device__ __forceinline__ int bucket_of(float px, float py, float pz) {
    int ix = min(max((int)(px * 16.0f), 0), 15);
    int iy = min(max((int)(py * 8.0f), 0), 7);
    int iz = min(max((int)(pz * 8.0f), 0), 7);
    return (ix * 8 + iy) * 8 + iz;
}

__global__ void __launch_bounds__(H_THREADS)
cvn_hist(const float* __restrict__ x, int* __restrict__ P, int n) {
    __shared__ int cnt[NB];
    int t = threadIdx.x;
    for (int q = t; q < NB; q += H_THREADS) cnt[q] = 0;
    __syncthreads();
    int base = blockIdx.x * PTS_PER_BLK;
    for (int k = 0; k < H_PPT; ++k) {
        int i = base + k * H_THREADS + t;
        if (i < n)
            atomicAdd(&cnt[bucket_of(x[3 * i], x[3 * i + 1], x[3 * i + 2])], 1);
    }
    __syncthreads();
    int* Pb = P + (size_t)blockIdx.x * NB;
    for (int q = t; q < NB; q += H_THREADS) Pb[q] = cnt[q];
}

__global__ void __launch_bounds__(256)
cvn_scan_a(const int* __restrict__ P, int* __restrict__ S, int nblk) {
    int q = blockIdx.x * 256 + threadIdx.x;
    int c = blockIdx.y;
    int b0 = c * CHUNK, b1 = min(b0 + CHUNK, nblk);
    int s = 0;
    for (int b = b0; b < b1; ++b) s += P[(size_t)b * NB + q];
    S[(size_t)c * NB + q] = s;
}

// After: S[c][q] = Texcl[q] + exclusive chunk prefix; S[0][q] = bucket base.
__global__ void __launch_bounds__(NB)
cvn_scan_b(int* __restrict__ S, int nch) {
    __shared__ int part[NB];
    int t = threadIdx.x;
    int acc = 0;
    for (int c = 0; c < nch; ++c) {
        int v = S[(size_t)c * NB + t];
        S[(size_t)c * NB + t] = acc;
        acc += v;
    }
    part[t] = acc;
    __syncthreads();
    for (int off = 1; off < NB; off <<= 1) {
        int v = (t >= off) ? part[t - off] : 0;
        __syncthreads();
        if (t >= off) part[t] += v;
        __syncthreads();
    }
    int texcl = (t == 0) ? 0 : part[t - 1];
    for (int c = 0; c < nch; ++c) S[(size_t)c * NB + t] += texcl;
}

__global__ void __launch_bounds__(256)
cvn_scan_c(int* __restrict__ P, const int* __restrict__ S, int nblk) {
    int q = blockIdx.x * 256 + threadIdx.x;
    int c = blockIdx.y;
    int b0 = c * CHUNK, b1 = min(b0 + CHUNK, nblk);
    int run = S[(size_t)c * NB + q];
    for (int b = b0; b < b1; ++b) {
        int v = P[(size_t)b * NB + q];
        P[(size_t)b * NB + q] = run;
        run += v;
    }
}

__global__ void __launch_bounds__(SC_THREADS)
cvn_scatter(const float* __restrict__ x, const int* __restrict__ P,
            float4* __restrict__ sorted, int* __restrict__ rank,
            int n, int write_rank) {
    __shared__ int cnt[NB];
    __shared__ int place[NB];
    __shared__ int Pb[NB];
    __shared__ int sc[NB];
    __shared__ float4 payload[PTS_PER_BLK];
    __shared__ unsigned short bkt[PTS_PER_BLK];
    int t = threadIdx.x, b = blockIdx.x;
    int base = b * PTS_PER_BLK;
    cnt[t] = 0; place[t] = 0;
    Pb[t] = P[(size_t)b * NB + t];
    __syncthreads();

    float px[SC_PPT], py[SC_PPT], pz[SC_PPT];
    int qq[SC_PPT];
    #pragma unroll
    for (int k = 0; k < SC_PPT; ++k) {
        int i = base + k * SC_THREADS + t;
        if (i < n) {
            px[k] = x[3 * i]; py[k] = x[3 * i + 1]; pz[k] = x[3 * i + 2];
            qq[k] = bucket_of(px[k], py[k], pz[k]);
            atomicAdd(&cnt[qq[k]], 1);
        } else qq[k] = -1;
    }
    __syncthreads();

    sc[t] = cnt[t];
    __syncthreads();
    for (int off = 1; off < NB; off <<= 1) {
        int v = (t >= off) ? sc[t - off] : 0;
        __syncthreads();
        if (t >= off) sc[t] += v;
        __syncthreads();
    }
    cnt[t] = (t == 0) ? 0 : sc[t - 1];
    __syncthreads();

    #pragma unroll
    for (int k = 0; k < SC_PPT; ++k) {
        if (qq[k] >= 0) {
            int q = qq[k];
            int lp = atomicAdd(&place[q], 1);
            int slot = cnt[q] + lp;
            int i = base + k * SC_THREADS + t;
            payload[slot] = make_float4(px[k], py[k], pz[k], __int_as_float(i));
            bkt[slot] = (unsigned short)q;
            if (write_rank) rank[i] = Pb[q] + lp;   // coalesced in i
        }
    }
    __syncthreads();

    int total = min(n - base, PTS_PER_BLK);
    #pragma unroll
    for (int k = 0; k < SC_PPT; ++k) {
        int j = k * SC_THREADS + t;
        if (j < total) {
            int q = bkt[j];
            sorted[Pb[q] + (j - cnt[q])] = payload[j];
        }
    }
}

__device__ __forceinline__ float4 lerp4(float4 a, float4 b, float w) {
    return make_float4(a.x + w * (b.x - a.x),
                       a.y + w * (b.y - a.y),
                       a.z + w * (b.z - a.z),
                       a.w + w * (b.w - a.w));
}

template <int RES>
__device__ __forceinline__ float4 level_val(const float4* __restrict__ V,
                                            float px, float py, float pz) {
    constexpr int S = RES + 1;
    float xs = fmodf(px * (float)RES, (float)RES);
    float ys = fmodf(py * (float)RES, (float)RES);
    float zs = fmodf(pz * (float)RES, (float)RES);
    float fx = floorf(xs), fy = floorf(ys), fz = floorf(zs);
    float tx = xs - fx, ty = ys - fy, tz = zs - fz;
    int ix = (int)fx, iy = (int)fy, iz = (int)fz;

    float wx = (3.0f - 2.0f * tx) * tx * tx;
    float wy = (3.0f - 2.0f * ty) * ty * ty;
    float wz = (3.0f - 2.0f * tz) * tz * tz;

    int base = (ix * S + iy) * S + iz;
    const float4* p0 = V + base;
    const float4* p1 = p0 + S * S;

    float4 c000 = p0[0];
    float4 c001 = p0[1];
    float4 c010 = p0[S];
    float4 c011 = p0[S + 1];
    float4 c100 = p1[0];
    float4 c101 = p1[1];
    float4 c110 = p1[S];
    float4 c111 = p1[S + 1];

    float4 m00 = lerp4(c000, c100, wx);
    float4 m01 = lerp4(c001, c101, wx);
    float4 m10 = lerp4(c010, c110, wx);
    float4 m11 = lerp4(c011, c111, wx);
    float4 n0  = lerp4(m00, m10, wy);
    float4 n1  = lerp4(m01, m11, wy);
    return lerp4(n0, n1, wz);
}

__device__ __forceinline__ float4 composite(const float4* __restrict__ V16,
                                            const float4* __restrict__ V32,
                                            const float4* __restrict__ V64,
                                            const float4* __restrict__ V128,
                                            float px, float py, float pz) {
    float4 acc = level_val<16>(V16, px, py, pz);
    float4 v;
    v = level_val<32>(V32, px, py, pz);
    acc.x += 0.5f * v.x; acc.y += 0.5f * v.y; acc.z += 0.5f * v.z; acc.w += 0.5f * v.w;
    v = level_val<64>(V64, px, py, pz);
    acc.x += 0.25f * v.x; acc.y += 0.25f * v.y; acc.z += 0.25f * v.z; acc.w += 0.25f * v.w;
    v = level_val<128>(V128, px, py, pz);
    acc.x += 0.125f * v.x; acc.y += 0.125f * v.y; acc.z += 0.125f * v.z; acc.w += 0.125f * v.w;
    return acc;
}

// Trilinear interp from an LDS slice covering one FULL coarse bucket
// (1/16 x 1/8 x 1/8). Per level: CX=RES/16 cells in x, CY=CZ=RES/8 in y/z.
template <int RES>
__device__ __forceinline__ float4 lds_interp_b(const float4* s,
                                               float px, float py, float pz,
                                               int ix16, int iy8, int iz8) {
    constexpr int CX = RES / 16, CY = RES / 8, CZ = RES / 8;
    constexpr int DY = CY + 1, DZ = CZ + 1;
    float xs = px * (float)RES;
    float ys = py * (float)RES;
    float zs = pz * (float)RES;
    int ixg = (int)xs, iyg = (int)ys, izg = (int)zs;
    float tx = xs - (float)ixg, ty = ys - (float)iyg, tz = zs - (float)izg;
    int lx = min(max(ixg - ix16 * CX, 0), CX - 1);
    int ly = min(max(iyg - iy8 * CY, 0), CY - 1);
    int lz = min(max(izg - iz8 * CZ, 0), CZ - 1);

    float wx = (3.0f - 2.0f * tx) * tx * tx;
    float wy = (3.0f - 2.0f * ty) * ty * ty;
    float wz = (3.0f - 2.0f * tz) * tz * tz;

    const float4* p0 = s + (lx * DY + ly) * DZ + lz;
    const float4* p1 = p0 + DY * DZ;
    float4 c000 = p0[0],  c001 = p0[1];
    float4 c010 = p0[DZ], c011 = p0[DZ + 1];
    float4 c100 = p1[0],  c101 = p1[1];
    float4 c110 = p1[DZ], c111 = p1[DZ + 1];

    float4 m00 = lerp4(c000, c100, wx);
    float4 m01 = lerp4(c001, c101, wx);
    float4 m10 = lerp4(c010, c110, wx);
    float4 m11 = lerp4(c011, c111, wx);
    float4 n0  = lerp4(m00, m10, wy);
    float4 n1  = lerp4(m01, m11, wy);
    return lerp4(n0, n1, wz);
}

// One WG per 1/16x1/8x1/8 bucket. Stage the full bucket's grid slices for
// all 4 levels (3099 float4 = 49.6 KB), one barrier, then stream sorted
// points coalesced -> evaluate LDS-only -> write tmp coalesced.
__global__ void __launch_bounds__(MT)
cvn_main4(const float4* __restrict__ sorted, const int* __restrict__ Tbase,
          const float4* __restrict__ V16, const float4* __restrict__ V32,
          const float4* __restrict__ V64, const float4* __restrict__ V128,
          float4* __restrict__ tmp, int n) {
    __shared__ float4 s128[9 * 17 * 17];   // 2601 -> 41616 B
    __shared__ float4 s64[5 * 9 * 9];      //  405 ->  6480 B
    __shared__ float4 s32[3 * 5 * 5];      //   75 ->  1200 B
    __shared__ float4 s16[2 * 3 * 3];      //   18 ->   288 B
    int t = threadIdx.x, b = blockIdx.x;

    // XCD-compact mapping: b&7 -> octant of the 16x8x8 bucket space
    // (8x4x4 buckets each); g enumerated x-slowest so the ~64 resident
    // buckets per XCD form a compact region (~2.2 MB V128 slice < 4MB L2).
    int ox = b & 1, oy = (b >> 1) & 1, oz = (b >> 2) & 1;
    int g  = b >> 3;                         // 0..127
    int gx = g >> 4, gy = (g >> 2) & 3, gz = g & 3;
    int ix16 = ox * 8 + gx, iy8 = oy * 4 + gy, iz8 = oz * 4 + gz;
    int q = (ix16 * 8 + iy8) * 8 + iz8;

    int base = Tbase[q];
    int end  = (q == NB - 1) ? n : Tbase[q + 1];
    int len  = end - base;

    // Stage: V128 slice 9x17x17 (z contiguous -> coalesced float4).
    int bx = ix16 * 8, by = iy8 * 16, bz = iz8 * 16;
    for (int u = t; u < 2601; u += MT) {
        int a = u / 289, r = u - a * 289;
        int bb = r / 17, c = r - bb * 17;
        s128[u] = V128[((size_t)(bx + a) * 129 + (by + bb)) * 129 + (bz + c)];
    }
    if (t < 405) {
        int a = t / 81, r = t - a * 81;
        int bb = r / 9, c = r - bb * 9;
        s64[t] = V64[((size_t)(ix16 * 4 + a) * 65 + (iy8 * 8 + bb)) * 65
                     + (iz8 * 8 + c)];
    } else if (t < 405 + 75) {
        int u = t - 405;
        int a = u / 25, r = u - a * 25;
        int bb = r / 5, c = r - bb * 5;
        s32[u] = V32[((size_t)(ix16 * 2 + a) * 33 + (iy8 * 4 + bb)) * 33
                     + (iz8 * 4 + c)];
    } else if (t < 405 + 75 + 18) {
        int u = t - 405 - 75;
        int a = u / 9, r = u - a * 9;
        int bb = r / 3, c = r - bb * 3;
        s16[u] = V16[((size_t)(ix16 + a) * 17 + (iy8 * 2 + bb)) * 17
                     + (iz8 * 2 + c)];
    }
    __syncthreads();

    // Stream points: coalesced read, LDS-only eval, coalesced write.
    for (int p = t; p < len; p += MT) {
        float4 pt = sorted[base + p];
        float4 acc = lds_interp_b<16>(s16, pt.x, pt.y, pt.z, ix16, iy8, iz8);
        float4 v;
        v = lds_interp_b<32>(s32, pt.x, pt.y, pt.z, ix16, iy8, iz8);
        acc.x += 0.5f * v.x; acc.y += 0.5f * v.y;
        acc.z += 0.5f * v.z; acc.w += 0.5f * v.w;
        v = lds_interp_b<64>(s64, pt.x, pt.y, pt.z, ix16, iy8, iz8);
        acc.x += 0.25f * v.x; acc.y += 0.25f * v.y;
        acc.z += 0.25f * v.z; acc.w += 0.25f * v.w;
        v = lds_interp_b<128>(s128, pt.x, pt.y, pt.z, ix16, iy8, iz8);
        acc.x += 0.125f * v.x; acc.y += 0.125f * v.y;
        acc.z += 0.125f * v.z; acc.w += 0.125f * v.w;
        tmp[base + p] = acc;
    }
}

// Mid-tier fallback: coarse-sorted order, scattered out write.
__global__ void __launch_bounds__(256)
cvn_main(const float4* __restrict__ sorted,
         const float4* __restrict__ V16, const float4* __restrict__ V32,
         const float4* __restrict__ V64, const float4* __restrict__ V128,
         float4* __restrict__ outbuf, int n, int nblocks) {
    int nb8 = nblocks >> 3;
    int c = (blockIdx.x & 7) * nb8 + (blockIdx.x >> 3);
    int j = c * 256 + (int)threadIdx.x;
    if (j >= n) return;
    float4 p = sorted[j];
    outbuf[__float_as_int(p.w)] = composite(V16, V32, V64, V128, p.x, p.y, p.z);
}

__global__ void __launch_bounds__(256)
cvn_permute(const float4* __restrict__ tmp, const int* __restrict__ rank,
            float4* __restrict__ out, int n) {
    int i = blockIdx.x * 256 + (int)threadIdx.x;
    if (i >= n) return;
    out[i] = tmp[rank[i]];
}

__global__ void __launch_bounds__(256)
cvn_direct(const float* __restrict__ x,
           const float4* __restrict__ V16, const float4* __restrict__ V32,
           const float4* __restrict__ V64, const float4* __restrict__ V128,
           float4* __restrict__ out, int n) {
    int i = blockIdx.x * blockDim.x + threadIdx.x;
    if (i >= n) return;
    out[i] = composite(V16, V32, V64, V128, x[3 * i], x[3 * i + 1], x[3 * i + 2]);
}

extern "C" void kernel_launch(void* const* d_in, const int* in_sizes, int n_in,
                              void* d_out, int out_size, void* d_ws, size_t ws_size,
                              hipStream_t stream) {
    const float*  x    = (const float*)d_in[0];
    const float4* V16  = (const float4*)d_in[1];
    const float4* V32  = (const float4*)d_in[2];
    const float4* V64  = (const float4*)d_in[3];
    const float4* V128 = (const float4*)d_in[4];
    float4* out = (float4*)d_out;

    int n = in_sizes[0] / 3;
    int nblk = (n + PTS_PER_BLK - 1) / PTS_PER_BLK;
    int nch  = (nblk + CHUNK - 1) / CHUNK;

    auto align256 = [](size_t v) { return (v + 255) & ~(size_t)255; };
    size_t offP      = 0;
    size_t offS      = align256(offP + (size_t)nblk * NB * sizeof(int));
    size_t offSorted = align256(offS + (size_t)nch * NB * sizeof(int));
    size_t offRank   = align256(offSorted + (size_t)n * sizeof(float4));
    size_t offTmp    = align256(offRank + (size_t)n * sizeof(int));
    size_t needFull  = offTmp + (size_t)n * sizeof(float4);
    size_t needMid   = offRank;

    int grid256 = (n + 255) / 256;
    int nblocks = ((grid256 + 7) / 8) * 8;

    if (ws_size >= needMid) {
        int*    P      = (int*)((char*)d_ws + offP);
        int*    S      = (int*)((char*)d_ws + offS);
        float4* sorted = (float4*)((char*)d_ws + offSorted);
        bool full = (ws_size >= needFull);
        int*    rank = full ? (int*)((char*)d_ws + offRank) : nullptr;
        float4* tmp  = full ? (float4*)((char*)d_ws + offTmp) : nullptr;

        cvn_hist<<<nblk, H_THREADS, 0, stream>>>(x, P, n);
        cvn_scan_a<<<dim3(NB / 256, nch), 256, 0, stream>>>(P, S, nblk);
        cvn_scan_b<<<1, NB, 0, stream>>>(S, nch);
        cvn_scan_c<<<dim3(NB / 256, nch), 256, 0, stream>>>(P, S, nblk);
        cvn_scatter<<<nblk, SC_THREADS, 0, stream>>>(x, P, sorted, rank, n,
                                                     full ? 1 : 0);
        if (full) {
            cvn_main4<<<NB, MT, 0, stream>>>(sorted, S, V16, V32, V64, V128,
                                             tmp, n);
            cvn_permute<<<grid256, 256, 0, stream>>>(tmp, rank, out, n);
        } else {
            cvn_main<<<nblocks, 256, 0, stream>>>(sorted, V16, V32, V64, V128,
                                                  out, n, nblocks);
        }
    } else {
        cvn_direct<<<grid256, 256, 0, stream>>>(x, V16, V32, V64, V128, out, n);
    }
}

// Round 3
// 187.698 us; speedup vs baseline: 1.2742x; 1.1692x over previous
//
#include <hip/hip_runtime.h>
#include <hip/hip_fp16.h>

// CompositeValueNoise R10b: 1024-bucket (16x8x8) counting sort; main kernel
// splits interpolation across pipes: V16/V32 read direct from global (slices
// are ~1.5KB -> L1-resident), V64/V128 staged to LDS as fp16 (ds_read_b64,
// ~3.5x less LDS-pipe work than R9's 32x b128). 24KB LDS + launch_bounds
// (512,8) -> 4 blocks/CU x 8 waves = 32 waves/CU, all 1024 blocks resident.
// Permute epilogue removed: main4 writes out[orig] directly (idx in pt.w),
// killing tmp (32MB W) + rank (16MB) + random-gather amplification.

#define NB 1024                // 16 x 8 x 8 buckets
#define PTS_PER_BLK 4096
#define CHUNK 32
#define SC_THREADS 1024
#define SC_PPT (PTS_PER_BLK / SC_THREADS)
#define H_THREADS 256
#define H_PPT (PTS_PER_BLK / H_THREADS)
#define MT 512                 // main kernel threads

__device__ __forceinline__ int bucket_of(float px, float py, float pz) {
    int ix = min(max((int)(px * 16.0f), 0), 15);
    int iy = min(max((int)(py * 8.0f), 0), 7);
    int iz = min(max((int)(pz * 8.0f), 0), 7);
    return (ix * 8 + iy) * 8 + iz;
}

__global__ void __launch_bounds__(H_THREADS)
cvn_hist(const float* __restrict__ x, int* __restrict__ P, int n) {
    __shared__ int cnt[NB];
    int t = threadIdx.x;
    for (int q = t; q < NB; q += H_THREADS) cnt[q] = 0;
    __syncthreads();
    int base = blockIdx.x * PTS_PER_BLK;
    for (int k = 0; k < H_PPT; ++k) {
        int i = base + k * H_THREADS + t;
        if (i < n)
            atomicAdd(&cnt[bucket_of(x[3 * i], x[3 * i + 1], x[3 * i + 2])], 1);
    }
    __syncthreads();
    int* Pb = P + (size_t)blockIdx.x * NB;
    for (int q = t; q < NB; q += H_THREADS) Pb[q] = cnt[q];
}

__global__ void __launch_bounds__(256)
cvn_scan_a(const int* __restrict__ P, int* __restrict__ S, int nblk) {
    int q = blockIdx.x * 256 + threadIdx.x;
    int c = blockIdx.y;
    int b0 = c * CHUNK, b1 = min(b0 + CHUNK, nblk);
    int s = 0;
    for (int b = b0; b < b1; ++b) s += P[(size_t)b * NB + q];
    S[(size_t)c * NB + q] = s;
}

// After: S[c][q] = Texcl[q] + exclusive chunk prefix; S[0][q] = bucket base.
__global__ void __launch_bounds__(NB)
cvn_scan_b(int* __restrict__ S, int nch) {
    __shared__ int part[NB];
    int t = threadIdx.x;
    int acc = 0;
    for (int c = 0; c < nch; ++c) {
        int v = S[(size_t)c * NB + t];
        S[(size_t)c * NB + t] = acc;
        acc += v;
    }
    part[t] = acc;
    __syncthreads();
    for (int off = 1; off < NB; off <<= 1) {
        int v = (t >= off) ? part[t - off] : 0;
        __syncthreads();
        if (t >= off) part[t] += v;
        __syncthreads();
    }
    int texcl = (t == 0) ? 0 : part[t - 1];
    for (int c = 0; c < nch; ++c) S[(size_t)c * NB + t] += texcl;
}

__global__ void __launch_bounds__(256)
cvn_scan_c(int* __restrict__ P, const int* __restrict__ S, int nblk) {
    int q = blockIdx.x * 256 + threadIdx.x;
    int c = blockIdx.y;
    int b0 = c * CHUNK, b1 = min(b0 + CHUNK, nblk);
    int run = S[(size_t)c * NB + q];
    for (int b = b0; b < b1; ++b) {
        int v = P[(size_t)b * NB + q];
        P[(size_t)b * NB + q] = run;
        run += v;
    }
}

__global__ void __launch_bounds__(SC_THREADS)
cvn_scatter(const float* __restrict__ x, const int* __restrict__ P,
            float4* __restrict__ sorted, int n) {
    __shared__ int cnt[NB];
    __shared__ int place[NB];
    __shared__ int Pb[NB];
    __shared__ int sc[NB];
    __shared__ float4 payload[PTS_PER_BLK];
    __shared__ unsigned short bkt[PTS_PER_BLK];
    int t = threadIdx.x, b = blockIdx.x;
    int base = b * PTS_PER_BLK;
    cnt[t] = 0; place[t] = 0;
    Pb[t] = P[(size_t)b * NB + t];
    __syncthreads();

    float px[SC_PPT], py[SC_PPT], pz[SC_PPT];
    int qq[SC_PPT];
    #pragma unroll
    for (int k = 0; k < SC_PPT; ++k) {
        int i = base + k * SC_THREADS + t;
        if (i < n) {
            px[k] = x[3 * i]; py[k] = x[3 * i + 1]; pz[k] = x[3 * i + 2];
            qq[k] = bucket_of(px[k], py[k], pz[k]);
            atomicAdd(&cnt[qq[k]], 1);
        } else qq[k] = -1;
    }
    __syncthreads();

    sc[t] = cnt[t];
    __syncthreads();
    for (int off = 1; off < NB; off <<= 1) {
        int v = (t >= off) ? sc[t - off] : 0;
        __syncthreads();
        if (t >= off) sc[t] += v;
        __syncthreads();
    }
    cnt[t] = (t == 0) ? 0 : sc[t - 1];
    __syncthreads();

    #pragma unroll
    for (int k = 0; k < SC_PPT; ++k) {
        if (qq[k] >= 0) {
            int q = qq[k];
            int lp = atomicAdd(&place[q], 1);
            int slot = cnt[q] + lp;
            int i = base + k * SC_THREADS + t;
            payload[slot] = make_float4(px[k], py[k], pz[k], __int_as_float(i));
            bkt[slot] = (unsigned short)q;
        }
    }
    __syncthreads();

    int total = min(n - base, PTS_PER_BLK);
    #pragma unroll
    for (int k = 0; k < SC_PPT; ++k) {
        int j = k * SC_THREADS + t;
        if (j < total) {
            int q = bkt[j];
            sorted[Pb[q] + (j - cnt[q])] = payload[j];
        }
    }
}

__device__ __forceinline__ float4 lerp4(float4 a, float4 b, float w) {
    return make_float4(a.x + w * (b.x - a.x),
                       a.y + w * (b.y - a.y),
                       a.z + w * (b.z - a.z),
                       a.w + w * (b.w - a.w));
}

template <int RES>
__device__ __forceinline__ float4 level_val(const float4* __restrict__ V,
                                            float px, float py, float pz) {
    constexpr int S = RES + 1;
    float xs = fmodf(px * (float)RES, (float)RES);
    float ys = fmodf(py * (float)RES, (float)RES);
    float zs = fmodf(pz * (float)RES, (float)RES);
    float fx = floorf(xs), fy = floorf(ys), fz = floorf(zs);
    float tx = xs - fx, ty = ys - fy, tz = zs - fz;
    int ix = (int)fx, iy = (int)fy, iz = (int)fz;

    float wx = (3.0f - 2.0f * tx) * tx * tx;
    float wy = (3.0f - 2.0f * ty) * ty * ty;
    float wz = (3.0f - 2.0f * tz) * tz * tz;

    int base = (ix * S + iy) * S + iz;
    const float4* p0 = V + base;
    const float4* p1 = p0 + S * S;

    float4 c000 = p0[0];
    float4 c001 = p0[1];
    float4 c010 = p0[S];
    float4 c011 = p0[S + 1];
    float4 c100 = p1[0];
    float4 c101 = p1[1];
    float4 c110 = p1[S];
    float4 c111 = p1[S + 1];

    float4 m00 = lerp4(c000, c100, wx);
    float4 m01 = lerp4(c001, c101, wx);
    float4 m10 = lerp4(c010, c110, wx);
    float4 m11 = lerp4(c011, c111, wx);
    float4 n0  = lerp4(m00, m10, wy);
    float4 n1  = lerp4(m01, m11, wy);
    return lerp4(n0, n1, wz);
}

__device__ __forceinline__ float4 composite(const float4* __restrict__ V16,
                                            const float4* __restrict__ V32,
                                            const float4* __restrict__ V64,
                                            const float4* __restrict__ V128,
                                            float px, float py, float pz) {
    float4 acc = level_val<16>(V16, px, py, pz);
    float4 v;
    v = level_val<32>(V32, px, py, pz);
    acc.x += 0.5f * v.x; acc.y += 0.5f * v.y; acc.z += 0.5f * v.z; acc.w += 0.5f * v.w;
    v = level_val<64>(V64, px, py, pz);
    acc.x += 0.25f * v.x; acc.y += 0.25f * v.y; acc.z += 0.25f * v.z; acc.w += 0.25f * v.w;
    v = level_val<128>(V128, px, py, pz);
    acc.x += 0.125f * v.x; acc.y += 0.125f * v.y; acc.z += 0.125f * v.z; acc.w += 0.125f * v.w;
    return acc;
}

// fp16 node load: 8B (4 halves) via one ds_read_b64.
__device__ __forceinline__ float4 ldh4(const uint2* p) {
    uint2 u = *p;
    __half2 h0 = *reinterpret_cast<const __half2*>(&u.x);
    __half2 h1 = *reinterpret_cast<const __half2*>(&u.y);
    float2 f0 = __half22float2(h0);
    float2 f1 = __half22float2(h1);
    return make_float4(f0.x, f0.y, f1.x, f1.y);
}

__device__ __forceinline__ uint2 sth4(float4 v) {
    __half2 h0 = __floats2half2_rn(v.x, v.y);
    __half2 h1 = __floats2half2_rn(v.z, v.w);
    uint2 u;
    u.x = *reinterpret_cast<unsigned int*>(&h0);
    u.y = *reinterpret_cast<unsigned int*>(&h1);
    return u;
}

// Trilinear interp from an fp16 LDS slice covering one FULL coarse bucket
// (1/16 x 1/8 x 1/8). CX=RES/16 cells in x, CY=CZ=RES/8 in y/z.
template <int RES>
__device__ __forceinline__ float4 lds_interp_h(const uint2* s,
                                               float px, float py, float pz,
                                               int ix16, int iy8, int iz8) {
    constexpr int CX = RES / 16, CY = RES / 8, CZ = RES / 8;
    constexpr int DY = CY + 1, DZ = CZ + 1;
    float xs = px * (float)RES;
    float ys = py * (float)RES;
    float zs = pz * (float)RES;
    int ixg = (int)xs, iyg = (int)ys, izg = (int)zs;
    float tx = xs - (float)ixg, ty = ys - (float)iyg, tz = zs - (float)izg;
    int lx = min(max(ixg - ix16 * CX, 0), CX - 1);
    int ly = min(max(iyg - iy8 * CY, 0), CY - 1);
    int lz = min(max(izg - iz8 * CZ, 0), CZ - 1);

    float wx = (3.0f - 2.0f * tx) * tx * tx;
    float wy = (3.0f - 2.0f * ty) * ty * ty;
    float wz = (3.0f - 2.0f * tz) * tz * tz;

    const uint2* p0 = s + (lx * DY + ly) * DZ + lz;
    const uint2* p1 = p0 + DY * DZ;
    float4 c000 = ldh4(p0),      c001 = ldh4(p0 + 1);
    float4 c010 = ldh4(p0 + DZ), c011 = ldh4(p0 + DZ + 1);
    float4 c100 = ldh4(p1),      c101 = ldh4(p1 + 1);
    float4 c110 = ldh4(p1 + DZ), c111 = ldh4(p1 + DZ + 1);

    float4 m00 = lerp4(c000, c100, wx);
    float4 m01 = lerp4(c001, c101, wx);
    float4 m10 = lerp4(c010, c110, wx);
    float4 m11 = lerp4(c011, c111, wx);
    float4 n0  = lerp4(m00, m10, wy);
    float4 n1  = lerp4(m01, m11, wy);
    return lerp4(n0, n1, wz);
}

// One WG per 1/16x1/8x1/8 bucket. Stage V64/V128 bucket slices to LDS as
// fp16 (24KB); V16/V32 slices (~1.5KB) read direct from global -> L1.
// Streams sorted points coalesced, writes out[orig] scattered (idx in .w).
__global__ void __launch_bounds__(MT, 8)
cvn_main4(const float4* __restrict__ sorted, const int* __restrict__ Tbase,
          const float4* __restrict__ V16, const float4* __restrict__ V32,
          const float4* __restrict__ V64, const float4* __restrict__ V128,
          float4* __restrict__ out, int n) {
    __shared__ uint2 s128[9 * 17 * 17];   // 2601 -> 20808 B
    __shared__ uint2 s64[5 * 9 * 9];      //  405 ->  3240 B
    int t = threadIdx.x, b = blockIdx.x;

    // XCD-compact mapping: b&7 -> octant of the 16x8x8 bucket space
    // (8x4x4 buckets each); g enumerated x-slowest so the ~64 resident
    // buckets per XCD form a compact region (~2.2 MB V128 slice < 4MB L2).
    int ox = b & 1, oy = (b >> 1) & 1, oz = (b >> 2) & 1;
    int g  = b >> 3;                         // 0..127
    int gx = g >> 4, gy = (g >> 2) & 3, gz = g & 3;
    int ix16 = ox * 8 + gx, iy8 = oy * 4 + gy, iz8 = oz * 4 + gz;
    int q = (ix16 * 8 + iy8) * 8 + iz8;

    int base = Tbase[q];
    int end  = (q == NB - 1) ? n : Tbase[q + 1];
    int len  = end - base;

    // Stage: V128 slice 9x17x17, V64 slice 5x9x9 (z contiguous, fp16 pack).
    int bx = ix16 * 8, by = iy8 * 16, bz = iz8 * 16;
    for (int u = t; u < 2601; u += MT) {
        int a = u / 289, r = u - a * 289;
        int bb = r / 17, c = r - bb * 17;
        s128[u] = sth4(V128[((size_t)(bx + a) * 129 + (by + bb)) * 129
                            + (bz + c)]);
    }
    for (int u = t; u < 405; u += MT) {
        int a = u / 81, r = u - a * 81;
        int bb = r / 9, c = r - bb * 9;
        s64[u] = sth4(V64[((size_t)(ix16 * 4 + a) * 65 + (iy8 * 8 + bb)) * 65
                          + (iz8 * 8 + c)]);
    }
    __syncthreads();

    // Stream points: coalesced read; V16/V32 via L1, V64/V128 via LDS fp16;
    // scattered out write (original index carried in pt.w).
    for (int p = t; p < len; p += MT) {
        float4 pt = sorted[base + p];
        float4 acc = level_val<16>(V16, pt.x, pt.y, pt.z);
        float4 v;
        v = level_val<32>(V32, pt.x, pt.y, pt.z);
        acc.x += 0.5f * v.x; acc.y += 0.5f * v.y;
        acc.z += 0.5f * v.z; acc.w += 0.5f * v.w;
        v = lds_interp_h<64>(s64, pt.x, pt.y, pt.z, ix16, iy8, iz8);
        acc.x += 0.25f * v.x; acc.y += 0.25f * v.y;
        acc.z += 0.25f * v.z; acc.w += 0.25f * v.w;
        v = lds_interp_h<128>(s128, pt.x, pt.y, pt.z, ix16, iy8, iz8);
        acc.x += 0.125f * v.x; acc.y += 0.125f * v.y;
        acc.z += 0.125f * v.z; acc.w += 0.125f * v.w;
        out[__float_as_int(pt.w)] = acc;
    }
}

__global__ void __launch_bounds__(256)
cvn_direct(const float* __restrict__ x,
           const float4* __restrict__ V16, const float4* __restrict__ V32,
           const float4* __restrict__ V64, const float4* __restrict__ V128,
           float4* __restrict__ out, int n) {
    int i = blockIdx.x * blockDim.x + threadIdx.x;
    if (i >= n) return;
    out[i] = composite(V16, V32, V64, V128, x[3 * i], x[3 * i + 1], x[3 * i + 2]);
}

extern "C" void kernel_launch(void* const* d_in, const int* in_sizes, int n_in,
                              void* d_out, int out_size, void* d_ws, size_t ws_size,
                              hipStream_t stream) {
    const float*  x    = (const float*)d_in[0];
    const float4* V16  = (const float4*)d_in[1];
    const float4* V32  = (const float4*)d_in[2];
    const float4* V64  = (const float4*)d_in[3];
    const float4* V128 = (const float4*)d_in[4];
    float4* out = (float4*)d_out;

    int n = in_sizes[0] / 3;
    int nblk = (n + PTS_PER_BLK - 1) / PTS_PER_BLK;
    int nch  = (nblk + CHUNK - 1) / CHUNK;

    auto align256 = [](size_t v) { return (v + 255) & ~(size_t)255; };
    size_t offP      = 0;
    size_t offS      = align256(offP + (size_t)nblk * NB * sizeof(int));
    size_t offSorted = align256(offS + (size_t)nch * NB * sizeof(int));
    size_t need      = offSorted + (size_t)n * sizeof(float4);

    int grid256 = (n + 255) / 256;

    if (ws_size >= need) {
        int*    P      = (int*)((char*)d_ws + offP);
        int*    S      = (int*)((char*)d_ws + offS);
        float4* sorted = (float4*)((char*)d_ws + offSorted);

        cvn_hist<<<nblk, H_THREADS, 0, stream>>>(x, P, n);
        cvn_scan_a<<<dim3(NB / 256, nch), 256, 0, stream>>>(P, S, nblk);
        cvn_scan_b<<<1, NB, 0, stream>>>(S, nch);
        cvn_scan_c<<<dim3(NB / 256, nch), 256, 0, stream>>>(P, S, nblk);
        cvn_scatter<<<nblk, SC_THREADS, 0, stream>>>(x, P, sorted, n);
        cvn_main4<<<NB, MT, 0, stream>>>(sorted, S, V16, V32, V64, V128,
                                         out, n);
    } else {
        cvn_direct<<<grid256, 256, 0, stream>>>(x, V16, V32, V64, V128, out, n);
    }
}